// Round 1
// baseline (33565.347 us; speedup 1.0000x reference)
//
#include <hip/hip_runtime.h>
#include <math.h>

#define NSEQ 2048
#define D 512
#define V 512
#define NB 8                    // blocks for sequential kernels
#define COLS_PER_BLK (D / NB)   // 64

// ---------------------------------------------------------------------------
// GEMM: out[t][j] = bias[j] + sum_k x[t][k] * W[k][j]
// x row = gather ? emb[nums[t]] : src[t].  Grid: nrows/TM blocks x 256 thr.
// ---------------------------------------------------------------------------
template <int TM>
__global__ void gemm_rows(const float* __restrict__ src,
                          const int* __restrict__ nums,
                          const float* __restrict__ emb,
                          const float* __restrict__ W,
                          const float* __restrict__ bias,
                          float* __restrict__ out)
{
    __shared__ float xs[TM][D];
    const int tid = threadIdx.x;               // 256
    const int r0 = blockIdx.x * TM;

    for (int m = 0; m < TM; ++m) {
        const int row = r0 + m;
        const float* xr = nums ? (emb + (size_t)nums[row] * D)
                               : (src + (size_t)row * D);
        for (int idx = tid; idx < D; idx += 256) xs[m][idx] = xr[idx];
    }
    __syncthreads();

    const int j0 = tid, j1 = tid + 256;
    float acc0[TM], acc1[TM];
#pragma unroll
    for (int m = 0; m < TM; ++m) { acc0[m] = 0.f; acc1[m] = 0.f; }

    for (int k = 0; k < D; ++k) {
        const float w0 = W[(size_t)k * D + j0];
        const float w1 = W[(size_t)k * D + j1];
#pragma unroll
        for (int m = 0; m < TM; ++m) {
            const float x = xs[m][k];
            acc0[m] += x * w0;
            acc1[m] += x * w1;
        }
    }
    const float bb0 = bias[j0], bb1 = bias[j1];
#pragma unroll
    for (int m = 0; m < TM; ++m) {
        out[(size_t)(r0 + m) * D + j0] = acc0[m] + bb0;
        out[(size_t)(r0 + m) * D + j1] = acc1[m] + bb1;
    }
}

// ---------------------------------------------------------------------------
// Sequential tanh RNN: h_t = tanh(X[t] + h_{t-1} @ Whh), Hout[t] = h_t.
// NB blocks x 512 threads. Block b owns columns [b*64, b*64+64).
// Wave w covers k in [w*64, w*64+64); lane l -> column jbase+l.
// Weights live in 64 VGPRs per thread. Cross-block sync: per-step arrive
// counters (device-scope release/acquire).
// ---------------------------------------------------------------------------
__global__ void rnn_seq(const float* __restrict__ X,
                        const float* __restrict__ Whh,
                        float* __restrict__ Hout,
                        int* __restrict__ arrive,
                        int nsteps)
{
    __shared__ float hsh[D];
    __shared__ float part[D];
    const int tid = threadIdx.x;      // 512
    const int w = tid >> 6, l = tid & 63;
    const int jbase = blockIdx.x * COLS_PER_BLK;

    float wreg[64];
#pragma unroll
    for (int t = 0; t < 64; ++t)
        wreg[t] = Whh[(size_t)(w * 64 + t) * D + jbase + l];

    for (int s = 0; s < nsteps; ++s) {
        if (s > 0) {
            while (__hip_atomic_load(&arrive[s - 1], __ATOMIC_ACQUIRE,
                                     __HIP_MEMORY_SCOPE_AGENT) < NB) {}
            hsh[tid] = Hout[(size_t)(s - 1) * D + tid];
        } else {
            hsh[tid] = 0.f;
        }
        __syncthreads();

        float acc = 0.f;
#pragma unroll
        for (int t = 0; t < 64; ++t)
            acc += hsh[(w << 6) + t] * wreg[t];
        part[(w << 6) + l] = acc;
        __syncthreads();

        if (w == 0) {
            float sum = 0.f;
#pragma unroll
            for (int ww = 0; ww < 8; ++ww) sum += part[(ww << 6) + l];
            const float g = tanhf(sum + X[(size_t)s * D + jbase + l]);
            Hout[(size_t)s * D + jbase + l] = g;
            __threadfence();
            if (l == 0)
                __hip_atomic_fetch_add(&arrive[s], 1, __ATOMIC_RELEASE,
                                       __HIP_MEMORY_SCOPE_AGENT);
        }
    }
}

// ---------------------------------------------------------------------------
// ETt[k*V + j] = exp(T[j*V + k])   (transposed so CRF weight preload is
// coalesced and matvec matches rnn_seq's layout)
// ---------------------------------------------------------------------------
__global__ void prep_ET(const float* __restrict__ T, float* __restrict__ ETt)
{
    const int j = blockIdx.x;
    const int k = threadIdx.x;
    ETt[(size_t)k * V + j] = __expf(T[(size_t)j * V + k]);
}

// ---------------------------------------------------------------------------
// CRF backward recursion, rewritten as matvec with ET = exp(T):
//   c_new[j] = O[i][j] + M + log( sum_k ET[j,k] * exp(c[k]-M) ),  M = max(c)
// i runs n-2 .. 0.  Same 8-block layout/sync as rnn_seq.
// Final output: c_final[BOS=0].
// ---------------------------------------------------------------------------
__global__ void crf_seq(const float* __restrict__ O,
                        const float* __restrict__ ETt,
                        float* __restrict__ Cbuf,
                        float* __restrict__ Msl,
                        int* __restrict__ arrive,
                        float* __restrict__ out)
{
    __shared__ float esh[V];
    __shared__ float part[V];
    const int tid = threadIdx.x;      // 512
    const int w = tid >> 6, l = tid & 63;
    const int jbase = blockIdx.x * COLS_PER_BLK;

    float wreg[64];
#pragma unroll
    for (int t = 0; t < 64; ++t)
        wreg[t] = ETt[(size_t)(w * 64 + t) * V + jbase + l];

    const int nsteps = NSEQ - 1;   // 2047
    // init: c[k] = -inf except c[EOS=1] = O[n-1][1]
    const float oEOS = O[(size_t)(NSEQ - 1) * V + 1];
    float creg = (tid == 1) ? oEOS : -1e30f;
    float M = oEOS;

    for (int s = 0; s < nsteps; ++s) {
        const int i = nsteps - 1 - s;           // n-2 .. 0
        esh[tid] = __expf(creg - M);
        __syncthreads();

        float acc = 0.f;
#pragma unroll
        for (int t = 0; t < 64; ++t)
            acc += esh[(w << 6) + t] * wreg[t];
        part[(w << 6) + l] = acc;
        __syncthreads();

        const bool last = (s == nsteps - 1);
        if (w == 0) {
            float sum = 0.f;
#pragma unroll
            for (int ww = 0; ww < 8; ++ww) sum += part[(ww << 6) + l];
            const float cn = O[(size_t)i * V + jbase + l] + M + __logf(sum);
            if (!last) {
                Cbuf[(size_t)s * V + jbase + l] = cn;
                float mx = cn;
                for (int off = 32; off > 0; off >>= 1)
                    mx = fmaxf(mx, __shfl_xor(mx, off, 64));
                if (l == 0) Msl[s * NB + blockIdx.x] = mx;
                __threadfence();
                if (l == 0)
                    __hip_atomic_fetch_add(&arrive[s], 1, __ATOMIC_RELEASE,
                                           __HIP_MEMORY_SCOPE_AGENT);
            } else {
                if (blockIdx.x == 0 && l == 0) out[0] = cn;   // c0[BOS]
            }
        }
        if (!last) {
            while (__hip_atomic_load(&arrive[s], __ATOMIC_ACQUIRE,
                                     __HIP_MEMORY_SCOPE_AGENT) < NB) {}
            creg = Cbuf[(size_t)s * V + tid];
            float mm = Msl[s * NB];
#pragma unroll
            for (int b = 1; b < NB; ++b) mm = fmaxf(mm, Msl[s * NB + b]);
            M = mm;
        }
    }
}

// ---------------------------------------------------------------------------
extern "C" void kernel_launch(void* const* d_in, const int* in_sizes, int n_in,
                              void* d_out, int out_size, void* d_ws, size_t ws_size,
                              hipStream_t stream)
{
    const int*   nums = (const int*)d_in[0];
    const float* emb  = (const float*)d_in[1];
    const float* Wxh1 = (const float*)d_in[2];
    const float* Whh1 = (const float*)d_in[3];
    const float* b1   = (const float*)d_in[4];
    const float* Wxh2 = (const float*)d_in[5];
    const float* Whh2 = (const float*)d_in[6];
    const float* b2   = (const float*)d_in[7];
    const float* Wl   = (const float*)d_in[8];
    const float* bl   = (const float*)d_in[9];
    const float* T    = (const float*)d_in[10];
    float* out = (float*)d_out;

    // workspace layout (fp32 elements)
    float* Xbuf = (float*)d_ws;                 // [NSEQ*D]  X1, later X2
    float* Gbuf = Xbuf + (size_t)NSEQ * D;      // [NSEQ*D]  G, later O
    float* Hbuf = Gbuf + (size_t)NSEQ * D;      // [NSEQ*D]  H
    float* ETt  = Hbuf + (size_t)NSEQ * D;      // [V*V]
    float* Cbuf = ETt + (size_t)V * V;          // [(NSEQ-1)*V]
    float* Msl  = Cbuf + (size_t)(NSEQ - 1) * V;// [(NSEQ-1)*NB]
    int*   flags = (int*)(Msl + (size_t)(NSEQ - 1) * NB);
    int* arrive1 = flags;                       // [NSEQ]
    int* arrive2 = flags + NSEQ;                // [NSEQ]
    int* arriveC = flags + 2 * NSEQ;            // [NSEQ-1]

    hipMemsetAsync(flags, 0, (size_t)3 * NSEQ * sizeof(int), stream);

    // X1 = gather(emb, nums) @ Wxh1 + b1
    gemm_rows<8><<<NSEQ / 8, 256, 0, stream>>>(nullptr, nums, emb, Wxh1, b1, Xbuf);
    // G = RNN1(X1)
    rnn_seq<<<NB, 512, 0, stream>>>(Xbuf, Whh1, Gbuf, arrive1, NSEQ);
    // X2 = G @ Wxh2 + b2   (reuse Xbuf)
    gemm_rows<8><<<NSEQ / 8, 256, 0, stream>>>(Gbuf, nullptr, nullptr, Wxh2, b2, Xbuf);
    // H = RNN2(X2)
    rnn_seq<<<NB, 512, 0, stream>>>(Xbuf, Whh2, Hbuf, arrive2, NSEQ);
    // O = H @ Wl + bl   (reuse Gbuf as O)
    gemm_rows<8><<<NSEQ / 8, 256, 0, stream>>>(Hbuf, nullptr, nullptr, Wl, bl, Gbuf);
    // ET transpose+exp
    prep_ET<<<V, V, 0, stream>>>(T, ETt);
    // CRF backward recursion -> out[0]
    crf_seq<<<NB, 512, 0, stream>>>(Gbuf, ETt, Cbuf, Msl, arriveC, out);
}

// Round 2
// 11948.830 us; speedup vs baseline: 2.8091x; 2.8091x over previous
//
#include <hip/hip_runtime.h>
#include <math.h>
#include <stdint.h>

#define NSEQ 2048
#define D 512
#define V 512
#define NB 8                    // blocks for sequential kernels
#define CPB (D / NB)            // 64 cols per block

// CRF tags must not collide with RNN tags (csync aliases sync1's memory)
#define CRF_TAG 0x8000u

// ---------------------------------------------------------------------------
// packed (tag,value) publish/poll — relaxed agent-scope atomics bypass the
// non-coherent L2s and carry their own validity tag, so no fences/invalidates
// are ever needed. Poison 0xAAAAAAAA never matches a tag.
// ---------------------------------------------------------------------------
__device__ __forceinline__ uint64_t pack_tv(float v, uint32_t tag) {
    return ((uint64_t)tag << 32) | (uint64_t)__float_as_uint(v);
}
__device__ __forceinline__ float poll_get(uint64_t* p, uint32_t tag) {
    while (true) {
        uint64_t u = __hip_atomic_load(p, __ATOMIC_RELAXED,
                                       __HIP_MEMORY_SCOPE_AGENT);
        if ((uint32_t)(u >> 32) == tag) return __uint_as_float((uint32_t)u);
    }
}
__device__ __forceinline__ void publish(uint64_t* p, float v, uint32_t tag) {
    __hip_atomic_store(p, pack_tv(v, tag), __ATOMIC_RELAXED,
                       __HIP_MEMORY_SCOPE_AGENT);
}

// ---------------------------------------------------------------------------
// GEMM: out[t][j] = bias[j] + sum_k x[t][k] * W[k][j]
// ---------------------------------------------------------------------------
template <int TM>
__global__ void gemm_rows(const float* __restrict__ src,
                          const int* __restrict__ nums,
                          const float* __restrict__ emb,
                          const float* __restrict__ W,
                          const float* __restrict__ bias,
                          float* __restrict__ out)
{
    __shared__ float xs[TM][D];
    const int tid = threadIdx.x;               // 256
    const int r0 = blockIdx.x * TM;

    for (int m = 0; m < TM; ++m) {
        const int row = r0 + m;
        const float* xr = nums ? (emb + (size_t)nums[row] * D)
                               : (src + (size_t)row * D);
        for (int idx = tid; idx < D; idx += 256) xs[m][idx] = xr[idx];
    }
    __syncthreads();

    const int j0 = tid, j1 = tid + 256;
    float acc0[TM], acc1[TM];
#pragma unroll
    for (int m = 0; m < TM; ++m) { acc0[m] = 0.f; acc1[m] = 0.f; }

    for (int k = 0; k < D; ++k) {
        const float w0 = W[(size_t)k * D + j0];
        const float w1 = W[(size_t)k * D + j1];
#pragma unroll
        for (int m = 0; m < TM; ++m) {
            const float x = xs[m][k];
            acc0[m] += x * w0;
            acc1[m] += x * w1;
        }
    }
    const float bb0 = bias[j0], bb1 = bias[j1];
#pragma unroll
    for (int m = 0; m < TM; ++m) {
        out[(size_t)(r0 + m) * D + j0] = acc0[m] + bb0;
        out[(size_t)(r0 + m) * D + j1] = acc1[m] + bb1;
    }
}

__device__ __forceinline__ float fast_tanh(float x) {
    // 1 - 2/(e^{2x}+1); saturates correctly at +-inf
    return 1.0f - 2.0f / (__expf(2.0f * x) + 1.0f);
}

// ---------------------------------------------------------------------------
// Sequential tanh RNN: h_t = tanh(X[t] + h_{t-1} @ Whh).
// NB blocks x 512 threads; block b owns cols [b*64,b*64+64).
// Wave w: FMA partial over k in [w*64,w*64+64) for all 64 cols; publish is
// split 8 cols per wave (lanes 0..7).
// ---------------------------------------------------------------------------
__global__ void rnn_seq(const float* __restrict__ X,
                        const float* __restrict__ Whh,
                        uint64_t* __restrict__ Hsync,
                        float* __restrict__ Hplain,
                        int nsteps)
{
    __shared__ float hsh[D];
    __shared__ float part[D];
    const int tid = threadIdx.x;      // 512
    const int w = tid >> 6, l = tid & 63;
    const int jbase = blockIdx.x * CPB;
    const int lcol = (w << 3) + (l & 7);       // local col for publish (l<8)
    const int gcol = jbase + lcol;
    const bool pub = (l < 8);

    float wreg[64];
#pragma unroll
    for (int t = 0; t < 64; ++t)
        wreg[t] = Whh[(size_t)(w * 64 + t) * D + jbase + l];

    for (int s = 0; s < nsteps; ++s) {
        // prefetch this step's X (latency hides under the poll)
        float xpre = pub ? X[(size_t)s * D + gcol] : 0.f;

        if (s == 0) hsh[tid] = 0.f;
        else        hsh[tid] = poll_get(&Hsync[(size_t)(s - 1) * D + tid],
                                        (uint32_t)(s - 1));
        __syncthreads();

        const float4* h4 = (const float4*)&hsh[w << 6];
        float a0 = 0.f, a1 = 0.f, a2 = 0.f, a3 = 0.f;
#pragma unroll
        for (int t = 0; t < 16; ++t) {
            float4 hv = h4[t];
            a0 += hv.x * wreg[4 * t + 0];
            a1 += hv.y * wreg[4 * t + 1];
            a2 += hv.z * wreg[4 * t + 2];
            a3 += hv.w * wreg[4 * t + 3];
        }
        part[tid] = (a0 + a1) + (a2 + a3);
        __syncthreads();

        if (pub) {
            float sum = 0.f;
#pragma unroll
            for (int ww = 0; ww < 8; ++ww) sum += part[(ww << 6) + lcol];
            const float g = fast_tanh(sum + xpre);
            publish(&Hsync[(size_t)s * D + gcol], g, (uint32_t)s);
            Hplain[(size_t)s * D + gcol] = g;
        }
    }
}

// ---------------------------------------------------------------------------
// ETt[k*V + j] = exp(T[j*V + k])
// ---------------------------------------------------------------------------
__global__ void prep_ET(const float* __restrict__ T, float* __restrict__ ETt)
{
    const int j = blockIdx.x;
    const int k = threadIdx.x;
    ETt[(size_t)k * V + j] = __expf(T[(size_t)j * V + k]);
}

// ---------------------------------------------------------------------------
// CRF backward recursion via exp-domain matvec:
//   c_new[j] = O[i][j] + M + log( sum_k ET[j,k] * exp(c[k]-M) ), M = max(c)
// ---------------------------------------------------------------------------
__global__ void crf_seq(const float* __restrict__ O,
                        const float* __restrict__ ETt,
                        uint64_t* __restrict__ Csync,
                        float* __restrict__ out)
{
    __shared__ float esh[V];
    __shared__ float part[V];
    __shared__ float wmax[8];
    const int tid = threadIdx.x;      // 512
    const int w = tid >> 6, l = tid & 63;
    const int jbase = blockIdx.x * CPB;
    const int lcol = (w << 3) + (l & 7);
    const int gcol = jbase + lcol;
    const bool pub = (l < 8);

    float wreg[64];
#pragma unroll
    for (int t = 0; t < 64; ++t)
        wreg[t] = ETt[(size_t)(w * 64 + t) * V + jbase + l];

    const int nsteps = NSEQ - 1;   // 2047
    const float oEOS = O[(size_t)(NSEQ - 1) * V + 1];
    float creg = (tid == 1) ? oEOS : -1e30f;

    for (int s = 0; s < nsteps; ++s) {
        const int i = nsteps - 1 - s;           // n-2 .. 0
        float opre = pub ? O[(size_t)i * V + gcol] : 0.f;

        if (s > 0)
            creg = poll_get(&Csync[(size_t)(s - 1) * V + tid],
                            CRF_TAG + (uint32_t)(s - 1));

        // block-wide max of c
        float mx = creg;
#pragma unroll
        for (int off = 32; off > 0; off >>= 1)
            mx = fmaxf(mx, __shfl_xor(mx, off, 64));
        if (l == 0) wmax[w] = mx;
        __syncthreads();
        float M = wmax[0];
#pragma unroll
        for (int ww = 1; ww < 8; ++ww) M = fmaxf(M, wmax[ww]);

        esh[tid] = __expf(creg - M);
        __syncthreads();

        const float4* e4 = (const float4*)&esh[w << 6];
        float a0 = 0.f, a1 = 0.f, a2 = 0.f, a3 = 0.f;
#pragma unroll
        for (int t = 0; t < 16; ++t) {
            float4 ev = e4[t];
            a0 += ev.x * wreg[4 * t + 0];
            a1 += ev.y * wreg[4 * t + 1];
            a2 += ev.z * wreg[4 * t + 2];
            a3 += ev.w * wreg[4 * t + 3];
        }
        part[tid] = (a0 + a1) + (a2 + a3);
        __syncthreads();

        if (pub) {
            float sum = 0.f;
#pragma unroll
            for (int ww = 0; ww < 8; ++ww) sum += part[(ww << 6) + lcol];
            const float cn = opre + M + __logf(sum);
            if (s < nsteps - 1) {
                publish(&Csync[(size_t)s * V + gcol], cn, CRF_TAG + (uint32_t)s);
            } else if (blockIdx.x == 0 && w == 0 && (l & 7) == 0 && l < 8) {
                out[0] = cn;   // c0[BOS], col 0
            }
        }
    }
}

// ---------------------------------------------------------------------------
extern "C" void kernel_launch(void* const* d_in, const int* in_sizes, int n_in,
                              void* d_out, int out_size, void* d_ws, size_t ws_size,
                              hipStream_t stream)
{
    const int*   nums = (const int*)d_in[0];
    const float* emb  = (const float*)d_in[1];
    const float* Wxh1 = (const float*)d_in[2];
    const float* Whh1 = (const float*)d_in[3];
    const float* b1   = (const float*)d_in[4];
    const float* Wxh2 = (const float*)d_in[5];
    const float* Whh2 = (const float*)d_in[6];
    const float* b2   = (const float*)d_in[7];
    const float* Wl   = (const float*)d_in[8];
    const float* bl   = (const float*)d_in[9];
    const float* T    = (const float*)d_in[10];
    float* out = (float*)d_out;

    // workspace layout (29 MB total)
    float* Xbuf  = (float*)d_ws;                 // [NSEQ*D]  X1, then X2
    float* GObuf = Xbuf + (size_t)NSEQ * D;      // [NSEQ*D]  G, then O
    float* Hbuf  = GObuf + (size_t)NSEQ * D;     // [NSEQ*D]  H
    float* ETt   = Hbuf + (size_t)NSEQ * D;      // [V*V]
    uint64_t* sync1 = (uint64_t*)(ETt + (size_t)V * V);   // [NSEQ*D] u64
    uint64_t* sync2 = sync1 + (size_t)NSEQ * D;           // [NSEQ*D] u64
    uint64_t* csync = sync1;   // alias — tags disjoint (CRF_TAG offset)

    // X1 = gather(emb, nums) @ Wxh1 + b1
    gemm_rows<8><<<NSEQ / 8, 256, 0, stream>>>(nullptr, nums, emb, Wxh1, b1, Xbuf);
    // G = RNN1(X1)
    rnn_seq<<<NB, 512, 0, stream>>>(Xbuf, Whh1, sync1, GObuf, NSEQ);
    // X2 = G @ Wxh2 + b2
    gemm_rows<8><<<NSEQ / 8, 256, 0, stream>>>(GObuf, nullptr, nullptr, Wxh2, b2, Xbuf);
    // H = RNN2(X2)
    rnn_seq<<<NB, 512, 0, stream>>>(Xbuf, Whh2, sync2, Hbuf, NSEQ);
    // O = H @ Wl + bl (into GObuf; G no longer needed)
    gemm_rows<8><<<NSEQ / 8, 256, 0, stream>>>(Hbuf, nullptr, nullptr, Wl, bl, GObuf);
    // ET transpose + exp
    prep_ET<<<V, V, 0, stream>>>(T, ETt);
    // CRF backward recursion -> out[0]
    crf_seq<<<NB, 512, 0, stream>>>(GObuf, ETt, csync, out);
}